// Round 5
// baseline (174.444 us; speedup 1.0000x reference)
//
#include <hip/hip_runtime.h>
#include <math.h>

#define NB 8
#define NT 2048
#define NE 1024
#define NH 64

typedef __attribute__((ext_vector_type(8))) short bh8;   // 8 x bf16 bits
typedef __attribute__((ext_vector_type(4))) float f4;    // MFMA accumulator

typedef unsigned short u16;

__device__ __forceinline__ u16 bf16rn(float f) {
    unsigned u = __float_as_uint(f);
    u += 0x7FFFu + ((u >> 16) & 1u);      // round-to-nearest-even
    return (u16)(u >> 16);
}
__device__ __forceinline__ float bf16f(u16 h) {
    return __uint_as_float(((unsigned)h) << 16);
}
// 16B-quad XOR swizzle within a 64-u16 (128B) row: returns u16 offset of quad start
__device__ __forceinline__ int swzq(int quad, int row) {
    return ((quad ^ (row & 7)) << 3);
}
// async global->LDS, 16B per lane; lds base must be wave-uniform (HW adds lane*16)
__device__ __forceinline__ void gll16(const u16* g, u16* l) {
    __builtin_amdgcn_global_load_lds(
        (const __attribute__((address_space(1))) unsigned int*)g,
        (__attribute__((address_space(3))) unsigned int*)l, 16, 0, 0);
}

// ---------------- Kernel 0: W -> (hi, lo) bf16, [192][1024], pre-swizzled ---
__global__ void wprep(const float* __restrict__ wq, const float* __restrict__ wk,
                      const float* __restrict__ wv,
                      u16* __restrict__ whi, u16* __restrict__ wlo)
{
    const int row = blockIdx.x;                       // 0..191
    const int k0  = threadIdx.x * 4;
    const float* src = (row < 64)  ? (wq + (size_t)row * NE)
                     : (row < 128) ? (wk + (size_t)(row - 64) * NE)
                     :               (wv + (size_t)(row - 128) * NE);
    float4 v = *(const float4*)(src + k0);
    ushort4 h, l;
    h.x = bf16rn(v.x); l.x = bf16rn(v.x - bf16f(h.x));
    h.y = bf16rn(v.y); l.y = bf16rn(v.y - bf16f(h.y));
    h.z = bf16rn(v.z); l.z = bf16rn(v.z - bf16f(h.z));
    h.w = bf16rn(v.w); l.w = bf16rn(v.w - bf16f(h.w));
    const int c   = k0 >> 6;                 // 64-col chunk
    const int kk  = k0 & 63;
    const int pos = c * 64 + swzq(kk >> 3, row) + (kk & 7);
    *(ushort4*)(whi + (size_t)row * NE + pos) = h;
    *(ushort4*)(wlo + (size_t)row * NE + pos) = l;
}

// ---------------- Kernel 1: QKV projection via split-bf16 MFMA ---------------
// 256 blocks x 256 thr. Block: 64 rows x 192 cols, BK=64, double-buffered LDS.
// Wave w: cols [48w,48w+48) x 64 rows (4 m-frags x 3 n-frags).
// 2-phase pipeline: issue next-tile W (global_load_lds) + X (regs) before
// computing current tile; one barrier per k-step.
__global__ __launch_bounds__(256, 1) void qkv_mfma(
    const float* __restrict__ x, const u16* __restrict__ whi_, const u16* __restrict__ wlo_,
    u16* __restrict__ qhi, u16* __restrict__ qlo,
    u16* __restrict__ khi, u16* __restrict__ klo, u16* __restrict__ vtp)
{
    __shared__ u16 xh[2][64][64], xl[2][64][64];     // 2 x 16 KB
    __shared__ u16 wh[2][192][64], wl[2][192][64];   // 2 x 48 KB  (total 128 KB)

    const int tid  = threadIdx.x;
    const int wid  = tid >> 6;
    const int lane = tid & 63;
    const int t15  = lane & 15, t4 = lane >> 4;
    const int row0 = blockIdx.x * 64;

    // W stage: 12 x global_load_lds width-16 (linear copy of pre-swizzled W)
    auto stageW = [&](int buf, int kt) {
#pragma unroll
        for (int it = 0; it < 6; ++it) {
            const int f = tid + it * 256;
            const int r = f >> 3, sg = f & 7;
            const size_t go = (size_t)r * NE + kt + sg * 8;
            u16* lb_h = &wh[buf][0][0] + (size_t)(wid * 64 + it * 256) * 8;
            u16* lb_l = &wl[buf][0][0] + (size_t)(wid * 64 + it * 256) * 8;
            gll16(whi_ + go, lb_h);
            gll16(wlo_ + go, lb_l);
        }
    };
    // X: issue-early to regs
    auto loadX = [&](int kt, float4* xr) {
#pragma unroll
        for (int it = 0; it < 4; ++it) {
            const int f = tid + it * 256;
            const int r = f >> 4, k0 = (f & 15) * 4;
            xr[it] = *(const float4*)(x + (size_t)(row0 + r) * NE + kt + k0);
        }
    };
    // X: write-late cvt -> swizzled LDS
    auto writeX = [&](int buf, const float4* xr) {
#pragma unroll
        for (int it = 0; it < 4; ++it) {
            const int f = tid + it * 256;
            const int r = f >> 4, k0 = (f & 15) * 4;
            const float4 v = xr[it];
            ushort4 h, l;
            h.x = bf16rn(v.x); l.x = bf16rn(v.x - bf16f(h.x));
            h.y = bf16rn(v.y); l.y = bf16rn(v.y - bf16f(h.y));
            h.z = bf16rn(v.z); l.z = bf16rn(v.z - bf16f(h.z));
            h.w = bf16rn(v.w); l.w = bf16rn(v.w - bf16f(h.w));
            const int pos = swzq(k0 >> 3, r) + (k0 & 7);
            *(ushort4*)&xh[buf][r][pos] = h;
            *(ushort4*)&xl[buf][r][pos] = l;
        }
    };

    const f4 fzero = {0.f, 0.f, 0.f, 0.f};
    f4 acc[4][3];
#pragma unroll
    for (int m = 0; m < 4; ++m)
#pragma unroll
        for (int n = 0; n < 3; ++n) acc[m][n] = fzero;

    // prologue: stage k-tile 0 into buffer 0
    {
        float4 xr[4];
        loadX(0, xr);
        stageW(0, 0);
        writeX(0, xr);
    }
    __syncthreads();

    for (int t = 0; t < 16; ++t) {
        const int c = t & 1, nb = c ^ 1;
        float4 xr[4];
        if (t < 15) {
            loadX((t + 1) * 64, xr);       // issue early (hides HBM under MFMA)
            stageW(nb, (t + 1) * 64);      // async into other buffer
        }

        // ---- compute current k-tile from buffer c ----
#pragma unroll
        for (int ks = 0; ks < 2; ++ks) {
            const int quad = 4 * ks + t4;
            bh8 ah[4], al[4];
#pragma unroll
            for (int m = 0; m < 4; ++m) {
                const int r = m * 16 + t15;
                ah[m] = *(const bh8*)&xh[c][r][swzq(quad, r)];
                al[m] = *(const bh8*)&xl[c][r][swzq(quad, r)];
            }
#pragma unroll
            for (int n = 0; n < 3; ++n) {
                const int cc = wid * 48 + n * 16 + t15;
                bh8 bhv = *(const bh8*)&wh[c][cc][swzq(quad, cc)];
                bh8 blv = *(const bh8*)&wl[c][cc][swzq(quad, cc)];
#pragma unroll
                for (int m = 0; m < 4; ++m) {
                    acc[m][n] = __builtin_amdgcn_mfma_f32_16x16x32_bf16(ah[m], bhv, acc[m][n], 0, 0, 0);
                    acc[m][n] = __builtin_amdgcn_mfma_f32_16x16x32_bf16(ah[m], blv, acc[m][n], 0, 0, 0);
                    acc[m][n] = __builtin_amdgcn_mfma_f32_16x16x32_bf16(al[m], bhv, acc[m][n], 0, 0, 0);
                }
            }
        }

        if (t < 15) writeX(nb, xr);        // write-late (after compute)
        __syncthreads();                   // drains gll vmcnt + ds writes
    }

    // epilogue: D layout col=lane&15, row=(lane>>4)*4+reg; outputs pre-swizzled
#pragma unroll
    for (int m = 0; m < 4; ++m) {
#pragma unroll
        for (int n = 0; n < 3; ++n) {
            const int col = wid * 48 + n * 16 + t15;
#pragma unroll
            for (int r = 0; r < 4; ++r) {
                const int row = row0 + m * 16 + t4 * 4 + r;
                float v = acc[m][n][r];
                if (col < 64) {
                    v *= 8.0f;                         // sqrt(head_size) folded into q
                    const u16 h = bf16rn(v);
                    const int pos = swzq(col >> 3, row) + (col & 7);
                    qhi[(size_t)row * NH + pos] = h;
                    qlo[(size_t)row * NH + pos] = bf16rn(v - bf16f(h));
                } else if (col < 128) {
                    const int cc  = col - 64;
                    const u16 h = bf16rn(v);
                    const int pos = swzq(cc >> 3, row) + (cc & 7);
                    khi[(size_t)row * NH + pos] = h;
                    klo[(size_t)row * NH + pos] = bf16rn(v - bf16f(h));
                } else {
                    const int hh  = col - 128;         // head dim
                    const int b   = row >> 11;
                    const int tok = row & (NT - 1);
                    const int cv  = tok & 63;
                    const int p   = (cv & 15) * 4 + (cv >> 4);       // PV permutation
                    const int tp  = (tok & ~63) | (swzq(p >> 3, hh) + (p & 7));
                    vtp[((size_t)b * NH + hh) * NT + tp] = bf16rn(v);
                }
            }
        }
    }
}

// ---------------- Kernel 2: MFMA flash attention, KV-split -------------------
// grid (80, 8) x 256 thr. q-tile 64 (wave w: rows 16w..16w+15), kv-tile 64.
// Per (b,qt): nch=(qt+8)/8 chunks, one block each. Double-buffered K/V staged
// via global_load_lds, prefetch next tile before computing current; one
// barrier per kv-tile.
__global__ __launch_bounds__(256, 2) void attn_mfma(
    const u16* __restrict__ qhi, const u16* __restrict__ qlo,
    const u16* __restrict__ khi, const u16* __restrict__ klo,
    const u16* __restrict__ vtp, const int* __restrict__ smp,
    float* __restrict__ out,
    float* __restrict__ po, float* __restrict__ pm, float* __restrict__ pl)
{
    __shared__ u16 kh[2][64][64], kl[2][64][64], vt[2][64][64];  // 48 KB
    __shared__ u16 ps[64][64];                                   // 8 KB

    const int tid  = threadIdx.x;
    const int wid  = tid >> 6;
    const int lane = tid & 63;
    const int t15  = lane & 15, t4 = lane >> 4;
    const int b    = blockIdx.y;
    const int u    = 79 - (int)blockIdx.x;       // heavy chunks dispatch first
    int qt, c;
    if (u < 8)       { qt = u;                   c = 0; }
    else if (u < 24) { qt = 8  + ((u - 8) >> 1); c = (u - 8) & 1; }
    else if (u < 48) { qt = 16 + (u - 24) / 3;   c = (u - 24) % 3; }
    else             { qt = 24 + ((u - 48) >> 2); c = (u - 48) & 3; }
    const int nch   = (qt + 8) >> 3;
    const int sm    = smp[0];
    const int total = sm ? (qt + 1) : (NT / 64);
    const int jt0   = c * total / nch;
    const int jt1   = (c + 1) * total / nch;
    const int qs    = qt * 64;

    const size_t bb = (size_t)b * NT;

    auto stageKV = [&](int buf, int js) {
#pragma unroll
        for (int it = 0; it < 2; ++it) {
            const int f = tid + it * 256;
            const int r = f >> 3, sg = f & 7;
            const size_t ck = (bb + js + r) * (size_t)NH + sg * 8;
            const size_t cv = ((size_t)b * NH + r) * NT + js + sg * 8;
            u16* lk = &kh[buf][0][0] + (size_t)(wid * 64 + it * 256) * 8;
            u16* ll = &kl[buf][0][0] + (size_t)(wid * 64 + it * 256) * 8;
            u16* lv = &vt[buf][0][0] + (size_t)(wid * 64 + it * 256) * 8;
            gll16(khi + ck, lk);
            gll16(klo + ck, ll);
            gll16(vtp + cv, lv);
        }
    };

    // hoist Q fragments from pre-swizzled global (row&7 == t15&7)
    bh8 qh[2], ql[2];
#pragma unroll
    for (int ks = 0; ks < 2; ++ks) {
        const size_t off = (bb + qs + wid * 16 + t15) * NH + swzq(4 * ks + t4, t15);
        qh[ks] = *(const bh8*)(qhi + off);
        ql[ks] = *(const bh8*)(qlo + off);
    }

    const f4 fzero = {0.f, 0.f, 0.f, 0.f};
    f4 o[4];
    float m_i[4], l_i[4];
#pragma unroll
    for (int i = 0; i < 4; ++i) { o[i] = fzero; m_i[i] = -INFINITY; l_i[i] = 0.f; }

    stageKV(0, jt0 * 64);
    __syncthreads();

    int cur = 0;
    for (int jt = jt0; jt < jt1; ++jt) {
        if (jt + 1 < jt1) stageKV(cur ^ 1, (jt + 1) * 64);   // async prefetch

        // S = (8q) k^T (split)
        f4 s[4];
#pragma unroll
        for (int n = 0; n < 4; ++n) s[n] = fzero;
#pragma unroll
        for (int n = 0; n < 4; ++n) {
#pragma unroll
            for (int ks = 0; ks < 2; ++ks) {
                const int rr = n * 16 + t15;
                bh8 bhv = *(const bh8*)&kh[cur][rr][swzq(4 * ks + t4, rr)];
                bh8 blv = *(const bh8*)&kl[cur][rr][swzq(4 * ks + t4, rr)];
                s[n] = __builtin_amdgcn_mfma_f32_16x16x32_bf16(qh[ks], bhv, s[n], 0, 0, 0);
                s[n] = __builtin_amdgcn_mfma_f32_16x16x32_bf16(qh[ks], blv, s[n], 0, 0, 0);
                s[n] = __builtin_amdgcn_mfma_f32_16x16x32_bf16(ql[ks], bhv, s[n], 0, 0, 0);
            }
        }

        // causal mask — only the diagonal tile (in the last chunk)
        if (sm && jt == qt) {
#pragma unroll
            for (int n = 0; n < 4; ++n) {
                const int col = n * 16 + t15;
#pragma unroll
                for (int r = 0; r < 4; ++r)
                    if (col > wid * 16 + t4 * 4 + r) s[n][r] = -INFINITY;
            }
        }

        // online softmax per row; stats across the 16-lane t15 groups
#pragma unroll
        for (int r = 0; r < 4; ++r) {
            float rm = fmaxf(fmaxf(s[0][r], s[1][r]), fmaxf(s[2][r], s[3][r]));
            rm = fmaxf(rm, __shfl_xor(rm, 1));
            rm = fmaxf(rm, __shfl_xor(rm, 2));
            rm = fmaxf(rm, __shfl_xor(rm, 4));
            rm = fmaxf(rm, __shfl_xor(rm, 8));
            const float mn = fmaxf(m_i[r], rm);
            const float cf = __expf(m_i[r] - mn);
            const float p0 = __expf(s[0][r] - mn);
            const float p1 = __expf(s[1][r] - mn);
            const float p2 = __expf(s[2][r] - mn);
            const float p3 = __expf(s[3][r] - mn);
            float rs = p0 + p1 + p2 + p3;
            rs += __shfl_xor(rs, 1);
            rs += __shfl_xor(rs, 2);
            rs += __shfl_xor(rs, 4);
            rs += __shfl_xor(rs, 8);
            l_i[r] = l_i[r] * cf + rs;
            m_i[r] = mn;
#pragma unroll
            for (int hs = 0; hs < 4; ++hs) o[hs][r] *= cf;
            ushort4 pw;
            pw.x = bf16rn(p0); pw.y = bf16rn(p1); pw.z = bf16rn(p2); pw.w = bf16rn(p3);
            const int R = wid * 16 + t4 * 4 + r;
            *(ushort4*)&ps[R][swzq(t15 >> 1, R) + (t15 & 1) * 4] = pw;
        }

        // O += P' V'  (permuted k-index matches vtp permutation; intra-wave ps)
#pragma unroll
        for (int ks = 0; ks < 2; ++ks) {
            const int pr = wid * 16 + t15;
            bh8 pa = *(const bh8*)&ps[pr][swzq(4 * ks + t4, pr)];
#pragma unroll
            for (int hs = 0; hs < 4; ++hs) {
                const int vr = hs * 16 + t15;
                bh8 bv = *(const bh8*)&vt[cur][vr][swzq(4 * ks + t4, vr)];
                o[hs] = __builtin_amdgcn_mfma_f32_16x16x32_bf16(pa, bv, o[hs], 0, 0, 0);
            }
        }

        __syncthreads();                   // drains prefetch gll + ps ordering
        cur ^= 1;
    }

    if (nch == 1) {
        // final: normalize + write fp32
#pragma unroll
        for (int r = 0; r < 4; ++r) {
            const float inv = 1.0f / l_i[r];
            const size_t rowoff = (bb + qs + wid * 16 + t4 * 4 + r) * NH;
#pragma unroll
            for (int hs = 0; hs < 4; ++hs)
                out[rowoff + hs * 16 + t15] = o[hs][r] * inv;
        }
    } else {
        // partial: unnormalized o + per-row (m, l)
        const int slot = (b * 24 + (qt - 8)) * 4 + c;
        float* pop = po + (size_t)slot * 64 * 64;
#pragma unroll
        for (int r = 0; r < 4; ++r) {
            const int rl = wid * 16 + t4 * 4 + r;
#pragma unroll
            for (int hs = 0; hs < 4; ++hs)
                pop[(size_t)rl * 64 + hs * 16 + t15] = o[hs][r];
            if (t15 == 0) {
                pm[(size_t)slot * 64 + rl] = m_i[r];
                pl[(size_t)slot * 64 + rl] = l_i[r];
            }
        }
    }
}

// ---------------- Kernel 3: combine KV-split partials ------------------------
__global__ void attn_combine(const float* __restrict__ po, const float* __restrict__ pm,
                             const float* __restrict__ pl, float* __restrict__ out)
{
    const int qt  = 8 + (int)blockIdx.x;
    const int b   = blockIdx.y;
    const int nch = (qt + 8) >> 3;
    const int tid = threadIdx.x;
    const int r   = tid >> 2;              // 0..63
    const int h0  = (tid & 3) * 16;        // 16 h per thread
    const int base = (b * 24 + (qt - 8)) * 4;

    float m[4], w[4];
    float M = -INFINITY;
#pragma unroll
    for (int cc = 0; cc < 4; ++cc) {
        m[cc] = (cc < nch) ? pm[(size_t)(base + cc) * 64 + r] : -INFINITY;
        M = fmaxf(M, m[cc]);
    }
    float denom = 0.f;
#pragma unroll
    for (int cc = 0; cc < 4; ++cc) {
        w[cc] = (cc < nch) ? __expf(m[cc] - M) : 0.f;
        denom += ((cc < nch) ? pl[(size_t)(base + cc) * 64 + r] : 0.f) * w[cc];
    }
    const float inv = 1.0f / denom;

    const size_t orow = ((size_t)b * NT + (size_t)qt * 64 + r) * NH;
#pragma unroll
    for (int v = 0; v < 4; ++v) {
        float4 acc = make_float4(0.f, 0.f, 0.f, 0.f);
#pragma unroll
        for (int cc = 0; cc < 4; ++cc) {
            if (cc < nch) {
                float4 pv = *(const float4*)(po + ((size_t)(base + cc) * 64 + r) * 64 + h0 + v * 4);
                acc.x += pv.x * w[cc]; acc.y += pv.y * w[cc];
                acc.z += pv.z * w[cc]; acc.w += pv.w * w[cc];
            }
        }
        acc.x *= inv; acc.y *= inv; acc.z *= inv; acc.w *= inv;
        *(float4*)(out + orow + h0 + v * 4) = acc;
    }
}

extern "C" void kernel_launch(void* const* d_in, const int* in_sizes, int n_in,
                              void* d_out, int out_size, void* d_ws, size_t ws_size,
                              hipStream_t stream)
{
    const float* x  = (const float*)d_in[0];
    const float* wq = (const float*)d_in[1];
    const float* wk = (const float*)d_in[2];
    const float* wv = (const float*)d_in[3];
    const int*   sm = (const int*)d_in[4];
    float* out = (float*)d_out;

    u16* whi = (u16*)d_ws;                       // [192][1024] (swizzled)
    u16* wlo = whi + (size_t)192 * NE;
    u16* qhi = wlo + (size_t)192 * NE;           // [B*T][64] each (swizzled)
    u16* qlo = qhi + (size_t)NB * NT * NH;
    u16* khi = qlo + (size_t)NB * NT * NH;
    u16* klo = khi + (size_t)NB * NT * NH;
    u16* vtp = klo + (size_t)NB * NT * NH;       // [B][64][2048] perm+swizzled
    float* po = (float*)(vtp + (size_t)NB * NT * NH);  // [8*24*4][64][64]
    float* pm = po + (size_t)NB * 24 * 4 * 64 * 64;    // [8*24*4][64]
    float* pl = pm + (size_t)NB * 24 * 4 * 64;

    wprep<<<dim3(192), 256, 0, stream>>>(wq, wk, wv, whi, wlo);
    qkv_mfma<<<dim3((NB * NT) / 64), 256, 0, stream>>>(x, whi, wlo, qhi, qlo, khi, klo, vtp);
    attn_mfma<<<dim3(80, NB), 256, 0, stream>>>(qhi, qlo, khi, klo, vtp, sm, out, po, pm, pl);
    attn_combine<<<dim3(24, NB), 256, 0, stream>>>(po, pm, pl, out);
}